// Round 1
// baseline (330.232 us; speedup 1.0000x reference)
//
#include <hip/hip_runtime.h>
#include <hip/hip_bf16.h>

typedef __attribute__((ext_vector_type(4))) float  f32x4;
typedef __attribute__((ext_vector_type(8))) __bf16 bf16x8;
typedef __attribute__((ext_vector_type(2))) __bf16 bf16x2;
typedef unsigned short ushort_t;
typedef unsigned int   uint_t;

#define S_LEN   4096
#define D_DIM   64
#define NTILE16 256   /* q-tiles of 16 rows per batch */

// Per-wave independent causal flash attention.
// wave-private LDS: Vt (64x64 bf16, transposed+swizzled) + P (16x64 bf16, swizzled)
__global__ __launch_bounds__(128) void fattn_kernel(
    const float* __restrict__ Qg, const float* __restrict__ Kg,
    const float* __restrict__ Vg, float* __restrict__ Og)
{
    __shared__ __align__(16) ushort_t smem[2 * 5120];

    const int tid  = threadIdx.x;
    const int w    = tid >> 6;
    const int lane = tid & 63;
    const int g    = lane >> 4;   // 4 groups of 16 lanes
    const int ln   = lane & 15;

    ushort_t* Vl = smem + w * 5120;   // 4096 ushorts: Vt[64][64]
    ushort_t* Pl = Vl + 4096;         // 1024 ushorts: P[16][64]

    const int bid   = blockIdx.x;
    const int batch = bid >> 6;
    const int j     = bid & 63;
    const int tbase = 2 * j + w;      // 0..127; paired with 255-tbase

    const size_t boff = (size_t)batch * S_LEN * D_DIM;
    const float* Qb = Qg + boff;
    const float* Kb = Kg + boff;
    const float* Vb = Vg + boff;
    float*       Ob = Og + boff;

    const float SCALE = 0.125f * 1.44269504088896340736f; // 1/sqrt(64) * log2(e)

    for (int pass = 0; pass < 2; ++pass) {
        const int tile16  = pass ? (NTILE16 - 1 - tbase) : tbase;
        const int q0      = tile16 << 4;
        const int n_tiles = (q0 + 16 + 63) >> 6;

        // ---- Q fragments (A-layout: m=ln, k=g*8+i within each 32-slice) ----
        bf16x8 qf[2];
        {
            const float* qp = Qb + (size_t)(q0 + ln) * D_DIM + g * 8;
            #pragma unroll
            for (int ds = 0; ds < 2; ++ds) {
                #pragma unroll
                for (int i = 0; i < 8; ++i)
                    qf[ds][i] = (__bf16)(qp[ds * 32 + i] * SCALE);
            }
        }

        f32x4 acco[4];
        #pragma unroll
        for (int nb = 0; nb < 4; ++nb) {
            acco[nb][0] = 0.f; acco[nb][1] = 0.f; acco[nb][2] = 0.f; acco[nb][3] = 0.f;
        }
        float mrun[4], lrun[4];
        #pragma unroll
        for (int i = 0; i < 4; ++i) { mrun[i] = -1e30f; lrun[i] = 0.f; }

        for (int t = 0; t < n_tiles; ++t) {
            const int kv0 = t << 6;

            // ensure previous tile's LDS reads/writes drained before overwrite
            asm volatile("s_waitcnt lgkmcnt(0)" ::: "memory");

            // ---- stage V transposed into LDS (bf16, swizzled) ----
            // lane -> (kv pair = lane&31, d-quad = it*2 + lane>>5): conflict-free b32 writes
            #pragma unroll
            for (int it = 0; it < 8; ++it) {
                const int idx = it * 64 + lane;
                const int kvp = idx & 31;
                const int dq  = idx >> 5;      // 0..15
                const float* vp = Vb + (size_t)(kv0 + kvp * 2) * D_DIM + dq * 4;
                float4 va  = *(const float4*)(vp);
                float4 vb2 = *(const float4*)(vp + D_DIM);
                const float* vaf = (const float*)&va;
                const float* vbf = (const float*)&vb2;
                #pragma unroll
                for (int x = 0; x < 4; ++x) {
                    const int d = dq * 4 + x;
                    bf16x2 pk;
                    pk[0] = (__bf16)vaf[x];
                    pk[1] = (__bf16)vbf[x];
                    const int u32idx = (d * 32 + kvp) ^ ((d & 7) << 2);
                    *(bf16x2*)((uint_t*)Vl + u32idx) = pk;
                }
            }

            // ---- QK^T : S[16 q][64 kv], K straight from global ----
            f32x4 accs[4];
            #pragma unroll
            for (int ns = 0; ns < 4; ++ns) {
                accs[ns][0] = 0.f; accs[ns][1] = 0.f; accs[ns][2] = 0.f; accs[ns][3] = 0.f;
            }
            #pragma unroll
            for (int ns = 0; ns < 4; ++ns) {
                const float* kp = Kb + (size_t)(kv0 + ns * 16 + ln) * D_DIM + g * 8;
                #pragma unroll
                for (int ds = 0; ds < 2; ++ds) {
                    bf16x8 kf;
                    #pragma unroll
                    for (int i = 0; i < 8; ++i)
                        kf[i] = (__bf16)kp[ds * 32 + i];
                    accs[ns] = __builtin_amdgcn_mfma_f32_16x16x32_bf16(qf[ds], kf, accs[ns], 0, 0, 0);
                }
            }

            // ---- causal mask (only the diagonal tile needs it) ----
            if (t == n_tiles - 1) {
                #pragma unroll
                for (int ns = 0; ns < 4; ++ns) {
                    const int kvg = kv0 + ns * 16 + ln;
                    #pragma unroll
                    for (int i = 0; i < 4; ++i) {
                        const int qg = q0 + g * 4 + i;
                        if (kvg > qg) accs[ns][i] = -1e30f;
                    }
                }
            }

            // ---- online softmax (rows live in 16-lane groups; 4 rows/lane) ----
            float alpha[4];
            #pragma unroll
            for (int i = 0; i < 4; ++i) {
                float mx = fmaxf(fmaxf(accs[0][i], accs[1][i]), fmaxf(accs[2][i], accs[3][i]));
                #pragma unroll
                for (int off = 1; off < 16; off <<= 1) mx = fmaxf(mx, __shfl_xor(mx, off));
                const float mnew = fmaxf(mrun[i], mx);
                alpha[i] = exp2f(mrun[i] - mnew);
                mrun[i]  = mnew;
                #pragma unroll
                for (int ns = 0; ns < 4; ++ns) accs[ns][i] = exp2f(accs[ns][i] - mnew);
                float rs = accs[0][i] + accs[1][i] + accs[2][i] + accs[3][i];
                #pragma unroll
                for (int off = 1; off < 16; off <<= 1) rs += __shfl_xor(rs, off);
                lrun[i] = lrun[i] * alpha[i] + rs;
            }

            // ---- P -> LDS (bf16, swizzled) ----
            #pragma unroll
            for (int i = 0; i < 4; ++i) {
                const int m = g * 4 + i;
                #pragma unroll
                for (int ns = 0; ns < 4; ++ns) {
                    const int col = ns * 16 + ln;
                    ((__bf16*)Pl)[(m * 64 + col) ^ ((m & 7) << 3)] = (__bf16)accs[ns][i];
                }
            }

            // ---- rescale O ----
            #pragma unroll
            for (int nb = 0; nb < 4; ++nb) {
                #pragma unroll
                for (int i = 0; i < 4; ++i) acco[nb][i] *= alpha[i];
            }

            // writes (P, Vt) must land before cross-lane reads
            asm volatile("s_waitcnt lgkmcnt(0)" ::: "memory");

            // ---- P fragments (A-layout) ----
            bf16x8 pf[2];
            #pragma unroll
            for (int ks = 0; ks < 2; ++ks)
                pf[ks] = *(const bf16x8*)&Pl[(ln * 64 + ks * 32 + g * 8) ^ ((ln & 7) << 3)];

            // ---- PV : O += P @ V ----
            #pragma unroll
            for (int nb = 0; nb < 4; ++nb) {
                const int dr = nb * 16 + ln;
                #pragma unroll
                for (int ks = 0; ks < 2; ++ks) {
                    bf16x8 vf = *(const bf16x8*)&Vl[(dr * 64 + ks * 32 + g * 8) ^ ((dr & 7) << 3)];
                    acco[nb] = __builtin_amdgcn_mfma_f32_16x16x32_bf16(pf[ks], vf, acco[nb], 0, 0, 0);
                }
            }
        }

        // ---- epilogue: normalize and store ----
        float inv[4];
        #pragma unroll
        for (int i = 0; i < 4; ++i) inv[i] = 1.0f / lrun[i];
        #pragma unroll
        for (int nb = 0; nb < 4; ++nb) {
            #pragma unroll
            for (int i = 0; i < 4; ++i)
                Ob[(size_t)(q0 + g * 4 + i) * D_DIM + nb * 16 + ln] = acco[nb][i] * inv[i];
        }
    }
}

extern "C" void kernel_launch(void* const* d_in, const int* in_sizes, int n_in,
                              void* d_out, int out_size, void* d_ws, size_t ws_size,
                              hipStream_t stream) {
    const float* q = (const float*)d_in[0];
    const float* k = (const float*)d_in[1];
    const float* v = (const float*)d_in[2];
    float* o = (float*)d_out;
    // grid: 4 batches * 64 blocks; 2 waves/block, each wave = q-tile pair (t, 255-t)
    hipLaunchKernelGGL(fattn_kernel, dim3(256), dim3(128), 0, stream, q, k, v, o);
}

// Round 2
// 140.741 us; speedup vs baseline: 2.3464x; 2.3464x over previous
//
#include <hip/hip_runtime.h>
#include <hip/hip_bf16.h>

typedef __attribute__((ext_vector_type(4))) float  f32x4;
typedef __attribute__((ext_vector_type(8))) __bf16 bf16x8;
typedef __attribute__((ext_vector_type(2))) __bf16 bf16x2;
typedef unsigned short ushort_t;
typedef unsigned int   uint_t;

#define S_LEN   4096
#define D_DIM   64
#define NTILE16 256   /* q-tiles of 16 rows per batch */
#define WPB     8     /* waves per block (kv-split factor) */
#define WREG    5120  /* ushorts of LDS per wave: Vt(4096) + P(1024) */

// One block = one 16-row q-tile. 8 waves split the causal KV range
// (strided by 8 kv-tiles of 64). Wave-private LDS regions; single
// __syncthreads() before the 8-way partial combine.
__global__ __launch_bounds__(512) void fattn_kernel(
    const float* __restrict__ Qg, const float* __restrict__ Kg,
    const float* __restrict__ Vg, float* __restrict__ Og)
{
    __shared__ __align__(16) ushort_t smem[WPB * WREG];   // 80 KiB

    const int tid  = threadIdx.x;
    const int w    = tid >> 6;
    const int lane = tid & 63;
    const int g    = lane >> 4;   // 4 groups of 16 lanes
    const int ln   = lane & 15;

    ushort_t* Vl = smem + w * WREG;   // 4096 ushorts: Vt[64][64] bf16 swizzled
    ushort_t* Pl = Vl + 4096;         // 1024 ushorts: P[16][64]  bf16 swizzled

    const int bid    = blockIdx.x;
    const int batch  = bid & 3;
    const int tile16 = (NTILE16 - 1) - (bid >> 2);   // longest q-tiles dispatch first (LPT)
    const int q0     = tile16 << 4;
    const int nkvt   = (q0 + 16 + 63) >> 6;          // causal kv extent in 64-tiles

    const size_t boff = (size_t)batch * S_LEN * D_DIM;
    const float* Qb = Qg + boff;
    const float* Kb = Kg + boff;
    const float* Vb = Vg + boff;
    float*       Ob = Og + boff;

    const float SCALE = 0.125f * 1.44269504088896340736f; // 1/sqrt(64) * log2(e)

    // ---- Q fragments (A-layout: m=ln, k=g*8+i within each 32-slice) ----
    bf16x8 qf[2];
    {
        const float* qp = Qb + (size_t)(q0 + ln) * D_DIM + g * 8;
        #pragma unroll
        for (int ds = 0; ds < 2; ++ds) {
            #pragma unroll
            for (int i = 0; i < 8; ++i)
                qf[ds][i] = (__bf16)(qp[ds * 32 + i] * SCALE);
        }
    }

    f32x4 acco[4];
    #pragma unroll
    for (int nb = 0; nb < 4; ++nb) {
        acco[nb][0] = 0.f; acco[nb][1] = 0.f; acco[nb][2] = 0.f; acco[nb][3] = 0.f;
    }
    float mrun[4], lrun[4];
    #pragma unroll
    for (int i = 0; i < 4; ++i) { mrun[i] = -1e30f; lrun[i] = 0.f; }

    for (int t = w; t < nkvt; t += WPB) {
        const int kv0 = t << 6;

        // ensure previous tile's LDS reads/writes drained before overwrite
        asm volatile("s_waitcnt lgkmcnt(0)" ::: "memory");

        // ---- stage V transposed into LDS (bf16, swizzled) ----
        #pragma unroll
        for (int it = 0; it < 8; ++it) {
            const int idx = it * 64 + lane;
            const int kvp = idx & 31;
            const int dq  = idx >> 5;      // 0..15
            const float* vp = Vb + (size_t)(kv0 + kvp * 2) * D_DIM + dq * 4;
            float4 va  = *(const float4*)(vp);
            float4 vb2 = *(const float4*)(vp + D_DIM);
            const float* vaf = (const float*)&va;
            const float* vbf = (const float*)&vb2;
            #pragma unroll
            for (int x = 0; x < 4; ++x) {
                const int d = dq * 4 + x;
                bf16x2 pk;
                pk[0] = (__bf16)vaf[x];
                pk[1] = (__bf16)vbf[x];
                const int u32idx = (d * 32 + kvp) ^ ((d & 7) << 2);
                *(bf16x2*)((uint_t*)Vl + u32idx) = pk;
            }
        }

        // ---- QK^T : S[16 q][64 kv], K straight from global ----
        f32x4 accs[4];
        #pragma unroll
        for (int ns = 0; ns < 4; ++ns) {
            accs[ns][0] = 0.f; accs[ns][1] = 0.f; accs[ns][2] = 0.f; accs[ns][3] = 0.f;
        }
        #pragma unroll
        for (int ns = 0; ns < 4; ++ns) {
            const float* kp = Kb + (size_t)(kv0 + ns * 16 + ln) * D_DIM + g * 8;
            #pragma unroll
            for (int ds = 0; ds < 2; ++ds) {
                bf16x8 kf;
                #pragma unroll
                for (int i = 0; i < 8; ++i)
                    kf[i] = (__bf16)kp[ds * 32 + i];
                accs[ns] = __builtin_amdgcn_mfma_f32_16x16x32_bf16(qf[ds], kf, accs[ns], 0, 0, 0);
            }
        }

        // ---- causal mask (only the diagonal kv-tile needs it) ----
        if (t == nkvt - 1) {
            #pragma unroll
            for (int ns = 0; ns < 4; ++ns) {
                const int kvg = kv0 + ns * 16 + ln;
                #pragma unroll
                for (int i = 0; i < 4; ++i) {
                    const int qg = q0 + g * 4 + i;
                    if (kvg > qg) accs[ns][i] = -1e30f;
                }
            }
        }

        // ---- online softmax (rows live in 16-lane groups; 4 rows/lane) ----
        float alpha[4];
        #pragma unroll
        for (int i = 0; i < 4; ++i) {
            float mx = fmaxf(fmaxf(accs[0][i], accs[1][i]), fmaxf(accs[2][i], accs[3][i]));
            #pragma unroll
            for (int off = 1; off < 16; off <<= 1) mx = fmaxf(mx, __shfl_xor(mx, off));
            const float mnew = fmaxf(mrun[i], mx);
            alpha[i] = exp2f(mrun[i] - mnew);
            mrun[i]  = mnew;
            #pragma unroll
            for (int ns = 0; ns < 4; ++ns) accs[ns][i] = exp2f(accs[ns][i] - mnew);
            float rs = accs[0][i] + accs[1][i] + accs[2][i] + accs[3][i];
            #pragma unroll
            for (int off = 1; off < 16; off <<= 1) rs += __shfl_xor(rs, off);
            lrun[i] = lrun[i] * alpha[i] + rs;
        }

        // ---- P -> LDS (bf16, swizzled) ----
        #pragma unroll
        for (int i = 0; i < 4; ++i) {
            const int m = g * 4 + i;
            #pragma unroll
            for (int ns = 0; ns < 4; ++ns) {
                const int col = ns * 16 + ln;
                ((__bf16*)Pl)[(m * 64 + col) ^ ((m & 7) << 3)] = (__bf16)accs[ns][i];
            }
        }

        // ---- rescale O ----
        #pragma unroll
        for (int nb = 0; nb < 4; ++nb) {
            #pragma unroll
            for (int i = 0; i < 4; ++i) acco[nb][i] *= alpha[i];
        }

        // writes (P, Vt) must land before cross-lane reads
        asm volatile("s_waitcnt lgkmcnt(0)" ::: "memory");

        // ---- P fragments (A-layout) ----
        bf16x8 pf[2];
        #pragma unroll
        for (int ks = 0; ks < 2; ++ks)
            pf[ks] = *(const bf16x8*)&Pl[(ln * 64 + ks * 32 + g * 8) ^ ((ln & 7) << 3)];

        // ---- PV : O += P @ V ----
        #pragma unroll
        for (int nb = 0; nb < 4; ++nb) {
            const int dr = nb * 16 + ln;
            #pragma unroll
            for (int ks = 0; ks < 2; ++ks) {
                bf16x8 vf = *(const bf16x8*)&Vl[(dr * 64 + ks * 32 + g * 8) ^ ((dr & 7) << 3)];
                acco[nb] = __builtin_amdgcn_mfma_f32_16x16x32_bf16(pf[ks], vf, acco[nb], 0, 0, 0);
            }
        }
    }

    // ---- write this wave's partial (m, l, unnormalized O) into own LDS region ----
    asm volatile("s_waitcnt lgkmcnt(0)" ::: "memory");
    {
        float* F = (float*)(smem + w * WREG);   // 1056 floats fit in 10240 B
        #pragma unroll
        for (int i = 0; i < 4; ++i) {
            if (ln == 0) {
                F[g * 4 + i]      = mrun[i];
                F[16 + g * 4 + i] = lrun[i];
            }
        }
        #pragma unroll
        for (int nb = 0; nb < 4; ++nb) {
            #pragma unroll
            for (int i = 0; i < 4; ++i)
                F[32 + (g * 4 + i) * 64 + nb * 16 + ln] = acco[nb][i];
        }
    }

    __syncthreads();

    // ---- combine 8 partials: 512 threads cover 16 rows x 64 dims, 2 each ----
    #pragma unroll
    for (int rep = 0; rep < 2; ++rep) {
        const int o = tid + rep * 512;
        const int r = o >> 6;
        const int d = o & 63;

        float M = -1e30f;
        #pragma unroll
        for (int w2 = 0; w2 < WPB; ++w2)
            M = fmaxf(M, ((const float*)(smem + w2 * WREG))[r]);

        float L = 0.f, val = 0.f;
        #pragma unroll
        for (int w2 = 0; w2 < WPB; ++w2) {
            const float* F2 = (const float*)(smem + w2 * WREG);
            const float al = exp2f(F2[r] - M);
            L   += F2[16 + r] * al;
            val += F2[32 + r * 64 + d] * al;
        }
        Ob[(size_t)(q0 + r) * D_DIM + d] = val / L;
    }
}

extern "C" void kernel_launch(void* const* d_in, const int* in_sizes, int n_in,
                              void* d_out, int out_size, void* d_ws, size_t ws_size,
                              hipStream_t stream) {
    const float* q = (const float*)d_in[0];
    const float* k = (const float*)d_in[1];
    const float* v = (const float*)d_in[2];
    float* o = (float*)d_out;
    // 1024 blocks = 4 batches x 256 q-tiles (longest-first), 8 waves each
    hipLaunchKernelGGL(fattn_kernel, dim3(1024), dim3(512), 0, stream, q, k, v, o);
}

// Round 3
// 81.024 us; speedup vs baseline: 4.0757x; 1.7370x over previous
//
#include <hip/hip_runtime.h>
#include <hip/hip_bf16.h>

typedef __attribute__((ext_vector_type(4))) float  f32x4;
typedef __attribute__((ext_vector_type(8))) __bf16 bf16x8;
typedef __attribute__((ext_vector_type(4))) __bf16 bf16x4;
typedef unsigned short ushort_t;
typedef unsigned int   uint_t;

#define S_LEN   4096
#define D_DIM   64
#define NTILE16 256   /* q-tiles of 16 rows per batch */
#define WPB     8     /* waves per block (kv-split factor) */
#define FSTRIDE 1088  /* floats of LDS per wave: P(512) reuse + combine(1056) */

// ---------------- pre-pass: f32 -> bf16 (Q scaled), V transposed ----------------
__global__ __launch_bounds__(256) void prep_kernel(
    const float* __restrict__ Qg, const float* __restrict__ Kg,
    const float* __restrict__ Vg,
    __bf16* __restrict__ Qbf, __bf16* __restrict__ Kbf, __bf16* __restrict__ Vt)
{
    __shared__ __bf16 vt_l[64][72];

    const float SCALE = 0.125f * 1.44269504088896340736f; // 1/sqrt(64) * log2(e)
    const int tid   = threadIdx.x;
    const int bid   = blockIdx.x;
    const int batch = bid >> 6;
    const int s0    = (bid & 63) << 6;
    const size_t boff = (size_t)batch * S_LEN * D_DIM;

    const float4* Qp = (const float4*)(Qg + boff + (size_t)s0 * D_DIM);
    const float4* Kp = (const float4*)(Kg + boff + (size_t)s0 * D_DIM);
    const float4* Vp = (const float4*)(Vg + boff + (size_t)s0 * D_DIM);
    bf16x4* Qo = (bf16x4*)(Qbf + boff + (size_t)s0 * D_DIM);
    bf16x4* Ko = (bf16x4*)(Kbf + boff + (size_t)s0 * D_DIM);

    #pragma unroll
    for (int c = 0; c < 4; ++c) {
        const int e = c * 256 + tid;          // 1024 float4s in the 64x64 tile
        float4 q4 = Qp[e];
        float4 k4 = Kp[e];
        float4 v4 = Vp[e];
        bf16x4 qo, ko;
        qo[0] = (__bf16)(q4.x * SCALE); qo[1] = (__bf16)(q4.y * SCALE);
        qo[2] = (__bf16)(q4.z * SCALE); qo[3] = (__bf16)(q4.w * SCALE);
        ko[0] = (__bf16)k4.x; ko[1] = (__bf16)k4.y;
        ko[2] = (__bf16)k4.z; ko[3] = (__bf16)k4.w;
        Qo[e] = qo; Ko[e] = ko;
        const int s = e >> 4;
        const int d = (e & 15) * 4;
        vt_l[d + 0][s] = (__bf16)v4.x;
        vt_l[d + 1][s] = (__bf16)v4.y;
        vt_l[d + 2][s] = (__bf16)v4.z;
        vt_l[d + 3][s] = (__bf16)v4.w;
    }
    __syncthreads();

    // write Vt rows: [batch][d][4096]
    const int d  = tid >> 2;
    const int sq = tid & 3;
    __bf16* vo = Vt + (size_t)batch * D_DIM * S_LEN + (size_t)d * S_LEN + s0 + sq * 16;
    bf16x8 a = *(const bf16x8*)&vt_l[d][sq * 16];
    bf16x8 b = *(const bf16x8*)&vt_l[d][sq * 16 + 8];
    *(bf16x8*)vo = a;
    *(bf16x8*)(vo + 8) = b;
}

// ---------------- main: per-wave kv-split causal flash attention ----------------
__global__ __launch_bounds__(512) void fattn_kernel(
    const __bf16* __restrict__ Qbf, const __bf16* __restrict__ Kbf,
    const __bf16* __restrict__ Vt, float* __restrict__ Og)
{
    __shared__ __align__(16) float smem_f[WPB * FSTRIDE];   // ~34 KiB

    const int tid  = threadIdx.x;
    const int w    = tid >> 6;
    const int lane = tid & 63;
    const int g    = lane >> 4;   // 4 groups of 16 lanes
    const int ln   = lane & 15;

    float*    F  = smem_f + w * FSTRIDE;
    ushort_t* Pl = (ushort_t*)F;      // 1024 ushorts: P[16][64] bf16 swizzled

    const int bid    = blockIdx.x;
    const int batch  = bid & 3;
    const int tile16 = (NTILE16 - 1) - (bid >> 2);   // longest q-tiles first (LPT)
    const int q0     = tile16 << 4;
    const int nkvt   = (q0 + 16 + 63) >> 6;          // causal kv extent in 64-tiles

    const size_t boff = (size_t)batch * S_LEN * D_DIM;
    const __bf16* Qb = Qbf + boff;
    const __bf16* Kb = Kbf + boff;
    const __bf16* Vb = Vt + boff;     // [64][4096] rows of d
    float*        Ob = Og  + boff;

    // ---- Q fragments (A-layout: m=ln, k=g*8+i within each 32-slice) ----
    bf16x8 qf[2];
    #pragma unroll
    for (int ds = 0; ds < 2; ++ds)
        qf[ds] = *(const bf16x8*)&Qb[(size_t)(q0 + ln) * D_DIM + ds * 32 + g * 8];

    f32x4 acco[4];
    #pragma unroll
    for (int nb = 0; nb < 4; ++nb) {
        acco[nb][0] = 0.f; acco[nb][1] = 0.f; acco[nb][2] = 0.f; acco[nb][3] = 0.f;
    }
    float mrun[4], lrun[4];
    #pragma unroll
    for (int i = 0; i < 4; ++i) { mrun[i] = -1e30f; lrun[i] = 0.f; }

    for (int t = w; t < nkvt; t += WPB) {
        const int kv0 = t << 6;

        // ---- V fragments (B-layout for PV): issue early, used after softmax ----
        bf16x8 vf[4][2];
        #pragma unroll
        for (int nb = 0; nb < 4; ++nb)
            #pragma unroll
            for (int ks = 0; ks < 2; ++ks)
                vf[nb][ks] = *(const bf16x8*)&Vb[(size_t)(nb * 16 + ln) * S_LEN + kv0 + ks * 32 + g * 8];

        // ---- QK^T : S[16 q][64 kv] ----
        f32x4 accs[4];
        #pragma unroll
        for (int ns = 0; ns < 4; ++ns) {
            accs[ns][0] = 0.f; accs[ns][1] = 0.f; accs[ns][2] = 0.f; accs[ns][3] = 0.f;
        }
        #pragma unroll
        for (int ns = 0; ns < 4; ++ns) {
            const __bf16* kp = Kb + (size_t)(kv0 + ns * 16 + ln) * D_DIM + g * 8;
            #pragma unroll
            for (int ds = 0; ds < 2; ++ds) {
                bf16x8 kf = *(const bf16x8*)(kp + ds * 32);
                accs[ns] = __builtin_amdgcn_mfma_f32_16x16x32_bf16(qf[ds], kf, accs[ns], 0, 0, 0);
            }
        }

        // ---- causal mask (only the diagonal kv-tile needs it) ----
        if (t == nkvt - 1) {
            #pragma unroll
            for (int ns = 0; ns < 4; ++ns) {
                const int kvg = kv0 + ns * 16 + ln;
                #pragma unroll
                for (int i = 0; i < 4; ++i) {
                    const int qg = q0 + g * 4 + i;
                    if (kvg > qg) accs[ns][i] = -1e30f;
                }
            }
        }

        // ---- online softmax (rows live in 16-lane groups; 4 rows/lane) ----
        float alpha[4];
        #pragma unroll
        for (int i = 0; i < 4; ++i) {
            float mx = fmaxf(fmaxf(accs[0][i], accs[1][i]), fmaxf(accs[2][i], accs[3][i]));
            #pragma unroll
            for (int off = 1; off < 16; off <<= 1) mx = fmaxf(mx, __shfl_xor(mx, off));
            const float mnew = fmaxf(mrun[i], mx);
            alpha[i] = exp2f(mrun[i] - mnew);
            mrun[i]  = mnew;
            #pragma unroll
            for (int ns = 0; ns < 4; ++ns) accs[ns][i] = exp2f(accs[ns][i] - mnew);
            float rs = accs[0][i] + accs[1][i] + accs[2][i] + accs[3][i];
            #pragma unroll
            for (int off = 1; off < 16; off <<= 1) rs += __shfl_xor(rs, off);
            lrun[i] = lrun[i] * alpha[i] + rs;
        }

        // previous iteration's P reads must drain before overwrite
        asm volatile("s_waitcnt lgkmcnt(0)" ::: "memory");

        // ---- P -> LDS (bf16, swizzled) ----
        #pragma unroll
        for (int i = 0; i < 4; ++i) {
            const int m = g * 4 + i;
            #pragma unroll
            for (int ns = 0; ns < 4; ++ns) {
                const int col = ns * 16 + ln;
                ((__bf16*)Pl)[(m * 64 + col) ^ ((m & 7) << 3)] = (__bf16)accs[ns][i];
            }
        }

        // ---- rescale O ----
        #pragma unroll
        for (int nb = 0; nb < 4; ++nb) {
            #pragma unroll
            for (int i = 0; i < 4; ++i) acco[nb][i] *= alpha[i];
        }

        // P writes must land before cross-lane reads
        asm volatile("s_waitcnt lgkmcnt(0)" ::: "memory");

        // ---- P fragments (A-layout) ----
        bf16x8 pf[2];
        #pragma unroll
        for (int ks = 0; ks < 2; ++ks)
            pf[ks] = *(const bf16x8*)&((__bf16*)Pl)[(ln * 64 + ks * 32 + g * 8) ^ ((ln & 7) << 3)];

        // ---- PV : O += P @ V ----
        #pragma unroll
        for (int nb = 0; nb < 4; ++nb) {
            #pragma unroll
            for (int ks = 0; ks < 2; ++ks)
                acco[nb] = __builtin_amdgcn_mfma_f32_16x16x32_bf16(pf[ks], vf[nb][ks], acco[nb], 0, 0, 0);
        }
    }

    // ---- write this wave's partial (m, l, unnormalized O) into own LDS region ----
    asm volatile("s_waitcnt lgkmcnt(0)" ::: "memory");
    #pragma unroll
    for (int i = 0; i < 4; ++i) {
        if (ln == 0) {
            F[g * 4 + i]      = mrun[i];
            F[16 + g * 4 + i] = lrun[i];
        }
    }
    #pragma unroll
    for (int nb = 0; nb < 4; ++nb) {
        #pragma unroll
        for (int i = 0; i < 4; ++i)
            F[32 + (g * 4 + i) * 64 + nb * 16 + ln] = acco[nb][i];
    }

    __syncthreads();

    // ---- combine 8 partials: 512 threads cover 16 rows x 64 dims, 2 each ----
    #pragma unroll
    for (int rep = 0; rep < 2; ++rep) {
        const int o = tid + rep * 512;
        const int r = o >> 6;
        const int d = o & 63;

        float M = -1e30f;
        #pragma unroll
        for (int w2 = 0; w2 < WPB; ++w2)
            M = fmaxf(M, smem_f[w2 * FSTRIDE + r]);

        float L = 0.f, val = 0.f;
        #pragma unroll
        for (int w2 = 0; w2 < WPB; ++w2) {
            const float* F2 = smem_f + w2 * FSTRIDE;
            const float al = exp2f(F2[r] - M);
            L   += F2[16 + r] * al;
            val += F2[32 + r * 64 + d] * al;
        }
        Ob[(size_t)(q0 + r) * D_DIM + d] = val / L;
    }
}

extern "C" void kernel_launch(void* const* d_in, const int* in_sizes, int n_in,
                              void* d_out, int out_size, void* d_ws, size_t ws_size,
                              hipStream_t stream) {
    const float* q = (const float*)d_in[0];
    const float* k = (const float*)d_in[1];
    const float* v = (const float*)d_in[2];
    float* o = (float*)d_out;

    __bf16* Qbf = (__bf16*)d_ws;                       // 4*4096*64 bf16 = 2 MB
    __bf16* Kbf = Qbf + (size_t)4 * S_LEN * D_DIM;     // 2 MB
    __bf16* Vt  = Kbf + (size_t)4 * S_LEN * D_DIM;     // 2 MB (transposed [b][d][s])

    hipLaunchKernelGGL(prep_kernel, dim3(256), dim3(256), 0, stream, q, k, v, Qbf, Kbf, Vt);
    // 1024 blocks = 4 batches x 256 q-tiles (longest-first), 8 waves each
    hipLaunchKernelGGL(fattn_kernel, dim3(1024), dim3(512), 0, stream, Qbf, Kbf, Vt, o);
}

// Round 4
// 76.121 us; speedup vs baseline: 4.3382x; 1.0644x over previous
//
#include <hip/hip_runtime.h>
#include <hip/hip_bf16.h>

typedef __attribute__((ext_vector_type(4))) float  f32x4;
typedef __attribute__((ext_vector_type(8))) __bf16 bf16x8;
typedef __attribute__((ext_vector_type(4))) __bf16 bf16x4;
typedef unsigned int uint_t;

#define S_LEN   4096
#define D_DIM   64
#define NTILE16 256
#define WPB     8     /* waves per block (kv-split factor) */
#define FSTRIDE 1056  /* floats of LDS per wave for the combine */

// ---------------- pre-pass: f32 -> bf16 (Q scaled), V transposed ----------------
__global__ __launch_bounds__(256) void prep_kernel(
    const float* __restrict__ Qg, const float* __restrict__ Kg,
    const float* __restrict__ Vg,
    __bf16* __restrict__ Qbf, __bf16* __restrict__ Kbf, __bf16* __restrict__ Vt)
{
    __shared__ __bf16 vt_l[64][72];

    const float SCALE = 0.125f * 1.44269504088896340736f; // 1/sqrt(64) * log2(e)
    const int tid   = threadIdx.x;
    const int bid   = blockIdx.x;
    const int batch = bid >> 6;
    const int s0    = (bid & 63) << 6;
    const size_t boff = (size_t)batch * S_LEN * D_DIM;

    const float4* Qp = (const float4*)(Qg + boff + (size_t)s0 * D_DIM);
    const float4* Kp = (const float4*)(Kg + boff + (size_t)s0 * D_DIM);
    const float4* Vp = (const float4*)(Vg + boff + (size_t)s0 * D_DIM);
    bf16x4* Qo = (bf16x4*)(Qbf + boff + (size_t)s0 * D_DIM);
    bf16x4* Ko = (bf16x4*)(Kbf + boff + (size_t)s0 * D_DIM);

    #pragma unroll
    for (int c = 0; c < 4; ++c) {
        const int e = c * 256 + tid;          // 1024 float4s in the 64x64 tile
        float4 q4 = Qp[e];
        float4 k4 = Kp[e];
        float4 v4 = Vp[e];
        bf16x4 qo, ko;
        qo[0] = (__bf16)(q4.x * SCALE); qo[1] = (__bf16)(q4.y * SCALE);
        qo[2] = (__bf16)(q4.z * SCALE); qo[3] = (__bf16)(q4.w * SCALE);
        ko[0] = (__bf16)k4.x; ko[1] = (__bf16)k4.y;
        ko[2] = (__bf16)k4.z; ko[3] = (__bf16)k4.w;
        Qo[e] = qo; Ko[e] = ko;
        const int s = e >> 4;
        const int d = (e & 15) * 4;
        vt_l[d + 0][s] = (__bf16)v4.x;
        vt_l[d + 1][s] = (__bf16)v4.y;
        vt_l[d + 2][s] = (__bf16)v4.z;
        vt_l[d + 3][s] = (__bf16)v4.w;
    }
    __syncthreads();

    const int d  = tid >> 2;
    const int sq = tid & 3;
    __bf16* vo = Vt + (size_t)batch * D_DIM * S_LEN + (size_t)d * S_LEN + s0 + sq * 16;
    *(bf16x8*)vo       = *(const bf16x8*)&vt_l[d][sq * 16];
    *(bf16x8*)(vo + 8) = *(const bf16x8*)&vt_l[d][sq * 16 + 8];
}

// ---------------- main: paired-tile, kv-split, register-dataflow FA ----------------
__global__ __launch_bounds__(512, 4) void fattn_kernel(
    const __bf16* __restrict__ Qbf, const __bf16* __restrict__ Kbf,
    const __bf16* __restrict__ Vt, float* __restrict__ Og)
{
    __shared__ __align__(16) float smem_f[WPB * FSTRIDE];   // 33792 B

    const int tid  = threadIdx.x;
    const int w    = tid >> 6;
    const int lane = tid & 63;
    const int g    = lane >> 4;   // 4 groups of 16 lanes
    const int ln   = lane & 15;
    const bool oddg = (g & 1);

    float* F = smem_f + w * FSTRIDE;

    const int bid   = blockIdx.x;
    const int batch = bid & 3;
    const int jpair = bid >> 2;           // 0..127 -> tiles (255-j, j): uniform work

    const size_t boff = (size_t)batch * S_LEN * D_DIM;
    const __bf16* Qb = Qbf + boff;
    const __bf16* Kb = Kbf + boff;
    const __bf16* Vb = Vt  + boff;        // [64][4096] rows of d
    float*        Ob = Og  + boff;

    for (int half = 0; half < 2; ++half) {
        const int tile16 = half ? jpair : (NTILE16 - 1 - jpair);
        const int q0     = tile16 << 4;
        const int nkvt   = (q0 + 16 + 63) >> 6;

        // Q fragments (B-operand: n=ln -> q, k = ds*32+g*8+i)
        bf16x8 qf[2];
        #pragma unroll
        for (int ds = 0; ds < 2; ++ds)
            qf[ds] = *(const bf16x8*)&Qb[(size_t)(q0 + ln) * D_DIM + ds * 32 + g * 8];

        f32x4 acco[4];
        #pragma unroll
        for (int nb = 0; nb < 4; ++nb) {
            acco[nb][0] = 0.f; acco[nb][1] = 0.f; acco[nb][2] = 0.f; acco[nb][3] = 0.f;
        }
        float mrun = -1e30f, lrun = 0.f;   // per-lane: q-row = q0 + ln

        for (int t = w; t < nkvt; t += WPB) {
            const int kv0 = t << 6;

            // ---- K fragments (A-operand: m=ln -> kv) ----
            bf16x8 kf[4][2];
            #pragma unroll
            for (int ns = 0; ns < 4; ++ns) {
                const __bf16* kp = Kb + (size_t)(kv0 + ns * 16 + ln) * D_DIM + g * 8;
                kf[ns][0] = *(const bf16x8*)kp;
                kf[ns][1] = *(const bf16x8*)(kp + 32);
            }
            // ---- V fragments (B-operand for PV), issued early ----
            bf16x8 vf[4][2];
            #pragma unroll
            for (int nb = 0; nb < 4; ++nb) {
                const __bf16* vp = Vb + (size_t)(nb * 16 + ln) * S_LEN + kv0 + g * 8;
                vf[nb][0] = *(const bf16x8*)vp;
                vf[nb][1] = *(const bf16x8*)(vp + 32);
            }

            // ---- swapped QK^T: accs = S^T[kv][q]; lane holds q=ln, kv=ns*16+g*4+i ----
            f32x4 accs[4];
            #pragma unroll
            for (int ns = 0; ns < 4; ++ns) {
                accs[ns][0] = 0.f; accs[ns][1] = 0.f; accs[ns][2] = 0.f; accs[ns][3] = 0.f;
                accs[ns] = __builtin_amdgcn_mfma_f32_16x16x32_bf16(kf[ns][0], qf[0], accs[ns], 0, 0, 0);
                accs[ns] = __builtin_amdgcn_mfma_f32_16x16x32_bf16(kf[ns][1], qf[1], accs[ns], 0, 0, 0);
            }

            // ---- causal mask (diagonal kv-tile only) ----
            if (t == nkvt - 1) {
                const int qg = q0 + ln;
                #pragma unroll
                for (int ns = 0; ns < 4; ++ns)
                    #pragma unroll
                    for (int i = 0; i < 4; ++i)
                        if (kv0 + ns * 16 + g * 4 + i > qg) accs[ns][i] = -1e30f;
            }

            // ---- lane-local online softmax (full q-row per lane, 4 replicas) ----
            float mx = accs[0][0];
            #pragma unroll
            for (int ns = 0; ns < 4; ++ns)
                #pragma unroll
                for (int i = 0; i < 4; ++i) mx = fmaxf(mx, accs[ns][i]);
            mx = fmaxf(mx, __shfl_xor(mx, 16));
            mx = fmaxf(mx, __shfl_xor(mx, 32));
            const float mnew  = fmaxf(mrun, mx);
            const float alpha = exp2f(mrun - mnew);
            mrun = mnew;
            float rs = 0.f;
            #pragma unroll
            for (int ns = 0; ns < 4; ++ns)
                #pragma unroll
                for (int i = 0; i < 4; ++i) {
                    accs[ns][i] = exp2f(accs[ns][i] - mnew);
                    rs += accs[ns][i];
                }
            rs += __shfl_xor(rs, 16);
            rs += __shfl_xor(rs, 32);
            lrun = lrun * alpha + rs;

            // ---- broadcast alpha to acco row layout (row = g*4+i) and rescale ----
            float ar[4];
            #pragma unroll
            for (int i = 0; i < 4; ++i)
                ar[i] = __shfl(alpha, (g << 4) + (g << 2) + i);
            #pragma unroll
            for (int nb = 0; nb < 4; ++nb)
                #pragma unroll
                for (int i = 0; i < 4; ++i) acco[nb][i] *= ar[i];

            // ---- P^T -> A-fragment transpose, fully in registers ----
            // c[ns][jp] = pack(P[kv=ns*16+g*4+2jp], P[..+2jp+1]) for q=ln
            uint_t c[4][2];
            #pragma unroll
            for (int ns = 0; ns < 4; ++ns)
                #pragma unroll
                for (int jp = 0; jp < 2; ++jp) {
                    float lo = accs[ns][2 * jp], hi = accs[ns][2 * jp + 1];
                    asm("v_cvt_pk_bf16_f32 %0, %1, %2" : "=v"(c[ns][jp]) : "v"(lo), "v"(hi));
                }
            union { uint_t u[4]; bf16x8 v; } pfu[2];
            #pragma unroll
            for (int ks = 0; ks < 2; ++ks)
                #pragma unroll
                for (int jp = 0; jp < 2; ++jp) {
                    uint_t a = c[2 * ks][jp], b = c[2 * ks + 1][jp];
                    asm volatile("v_permlane32_swap_b32 %0, %1" : "+v"(a), "+v"(b));
                    const uint_t rax = (uint_t)__shfl_xor((int)a, 16);
                    const uint_t rbx = (uint_t)__shfl_xor((int)b, 16);
                    pfu[ks].u[jp]     = oddg ? rbx : a;    // k = g*8 + 2jp
                    pfu[ks].u[2 + jp] = oddg ? b   : rax;  // k = g*8 + 4 + 2jp
                }

            // ---- PV : O += P @ V ----
            #pragma unroll
            for (int nb = 0; nb < 4; ++nb) {
                acco[nb] = __builtin_amdgcn_mfma_f32_16x16x32_bf16(pfu[0].v, vf[nb][0], acco[nb], 0, 0, 0);
                acco[nb] = __builtin_amdgcn_mfma_f32_16x16x32_bf16(pfu[1].v, vf[nb][1], acco[nb], 0, 0, 0);
            }
        }

        // ---- partial write: per-row m, l via shuffle; O already row-indexed ----
        float mr[4], lr[4];
        #pragma unroll
        for (int i = 0; i < 4; ++i) {
            const int srcl = (g << 4) + (g << 2) + i;
            mr[i] = __shfl(mrun, srcl);
            lr[i] = __shfl(lrun, srcl);
        }
        if (ln == 0) {
            #pragma unroll
            for (int i = 0; i < 4; ++i) {
                F[g * 4 + i]      = mr[i];
                F[16 + g * 4 + i] = lr[i];
            }
        }
        #pragma unroll
        for (int nb = 0; nb < 4; ++nb)
            #pragma unroll
            for (int i = 0; i < 4; ++i)
                F[32 + (g * 4 + i) * 64 + nb * 16 + ln] = acco[nb][i];

        __syncthreads();

        // ---- combine 8 partials: 512 threads cover 16 rows x 64 dims, 2 each ----
        #pragma unroll
        for (int rep = 0; rep < 2; ++rep) {
            const int o = tid + rep * 512;
            const int r = o >> 6;
            const int d = o & 63;

            float M = -1e30f;
            #pragma unroll
            for (int w2 = 0; w2 < WPB; ++w2)
                M = fmaxf(M, smem_f[w2 * FSTRIDE + r]);

            float L = 0.f, val = 0.f;
            #pragma unroll
            for (int w2 = 0; w2 < WPB; ++w2) {
                const float* F2 = smem_f + w2 * FSTRIDE;
                const float al = exp2f(F2[r] - M);
                L   += F2[16 + r] * al;
                val += F2[32 + r * 64 + d] * al;
            }
            Ob[(size_t)(q0 + r) * D_DIM + d] = val / L;
        }

        __syncthreads();   // protect smem before second half overwrites
    }
}

extern "C" void kernel_launch(void* const* d_in, const int* in_sizes, int n_in,
                              void* d_out, int out_size, void* d_ws, size_t ws_size,
                              hipStream_t stream) {
    const float* q = (const float*)d_in[0];
    const float* k = (const float*)d_in[1];
    const float* v = (const float*)d_in[2];
    float* o = (float*)d_out;

    __bf16* Qbf = (__bf16*)d_ws;                       // 2 MB
    __bf16* Kbf = Qbf + (size_t)4 * S_LEN * D_DIM;     // 2 MB
    __bf16* Vt  = Kbf + (size_t)4 * S_LEN * D_DIM;     // 2 MB (transposed [b][d][s])

    hipLaunchKernelGGL(prep_kernel, dim3(256), dim3(256), 0, stream, q, k, v, Qbf, Kbf, Vt);
    // 512 blocks = 4 batches x 128 tile-pairs (j, 255-j); 8 waves kv-split each
    hipLaunchKernelGGL(fattn_kernel, dim3(512), dim3(512), 0, stream, Qbf, Kbf, Vt, o);
}